// Round 5
// baseline (658.249 us; speedup 1.0000x reference)
//
#include <hip/hip_runtime.h>

typedef float  f32x4 __attribute__((ext_vector_type(4)));
typedef _Float16 half8 __attribute__((ext_vector_type(8)));
typedef _Float16 half4 __attribute__((ext_vector_type(4)));

#define BN_EPS 1e-5f
#define NGRAPH 64

// ---------------------------------------------------------------- weights prep
struct PrepArgs {
    const float* src[8];
    _Float16*    dst[8];
    int          K[8];
};

// transpose [K][256] f32 -> [256][K] fp16, dst-major (coalesced writes)
__global__ void prep_weights(PrepArgs a) {
    int m = blockIdx.y;
    int K = a.K[m];
    int total = K << 8;
    int idx = blockIdx.x * blockDim.x + threadIdx.x;
    if (idx >= total) return;
    int n = idx / K;
    int k = idx - n * K;
    a.dst[m][idx] = (_Float16)a.src[m][(size_t)k * 256 + n];
}

__global__ void cast_x(const float* __restrict__ x, _Float16* __restrict__ o, int total) {
    int i = (blockIdx.x * blockDim.x + threadIdx.x) << 3;
    if (i >= total) return;
    f32x4 a = *(const f32x4*)(x + i);
    f32x4 b = *(const f32x4*)(x + i + 4);
    half8 r;
#pragma unroll
    for (int k = 0; k < 4; ++k) { r[k] = (_Float16)a[k]; r[k + 4] = (_Float16)b[k]; }
    *(half8*)(o + i) = r;
}

// ---------------------------------------------------------------- CSR build
// count + rank in one pass: rank[e] = position of edge e within its dst segment.
__global__ void edge_count(const int* __restrict__ ei, int* __restrict__ cnt,
                           int* __restrict__ rank, int E) {
    int e = blockIdx.x * blockDim.x + threadIdx.x;
    if (e < E) rank[e] = atomicAdd(&cnt[ei[E + e]], 1);
}

__global__ void scan_p1(const int* __restrict__ cnt, int* __restrict__ part, int N) {
    __shared__ int lds[256];
    int idx = blockIdx.x * 256 + threadIdx.x;
    lds[threadIdx.x] = (idx < N) ? cnt[idx] : 0;
    __syncthreads();
    for (int d = 128; d > 0; d >>= 1) {
        if (threadIdx.x < d) lds[threadIdx.x] += lds[threadIdx.x + d];
        __syncthreads();
    }
    if (threadIdx.x == 0) part[blockIdx.x] = lds[0];
}

__global__ void scan_p2(int* __restrict__ part, int* __restrict__ off, int N, int nb) {
    __shared__ int lds[256];
    int t = threadIdx.x;
    int v = (t < nb) ? part[t] : 0;
    lds[t] = v;
    __syncthreads();
    for (int d = 1; d < 256; d <<= 1) {
        int a = (t >= d) ? lds[t - d] : 0;
        __syncthreads();
        lds[t] += a;
        __syncthreads();
    }
    if (t < nb) part[t] = lds[t] - v;       // exclusive
    if (t == nb - 1) off[N] = lds[t];       // total = E
}

__global__ void scan_p3(const int* __restrict__ cnt, const int* __restrict__ part,
                        int* __restrict__ off, int N) {
    __shared__ int lds[256];
    int t = threadIdx.x;
    int idx = blockIdx.x * 256 + t;
    int v = (idx < N) ? cnt[idx] : 0;
    lds[t] = v;
    __syncthreads();
    for (int d = 1; d < 256; d <<= 1) {
        int a = (t >= d) ? lds[t - d] : 0;
        __syncthreads();
        lds[t] += a;
        __syncthreads();
    }
    if (idx < N) off[idx] = part[blockIdx.x] + lds[t] - v;
}

// atomic-free fill: slot = off[dst] + rank
__global__ void edge_fill(const int* __restrict__ ei, const int* __restrict__ off,
                          const int* __restrict__ rank, int* __restrict__ csr_src, int E) {
    int e = blockIdx.x * blockDim.x + threadIdx.x;
    if (e >= E) return;
    csr_src[off[ei[E + e]] + rank[e]] = ei[e];
}

// ---------------------------------------------------------------- gathers
// layer 0: fp16 x, 128 feats -> quarter-wave per row, 8 row-loads in flight/wave
__global__ void gather0(const _Float16* __restrict__ x, const int* __restrict__ off,
                        const int* __restrict__ srcs, _Float16* __restrict__ out, int N) {
    int wid = (blockIdx.x << 2) + (threadIdx.x >> 6);
    if (wid >= N) return;
    int lane = threadIdx.x & 63;
    int q = lane >> 4;
    int fb = (lane & 15) << 3;               // 8 fp16, 128 feats
    float acc[8] = {0.f, 0.f, 0.f, 0.f, 0.f, 0.f, 0.f, 0.f};
    int end = off[wid + 1];
    int e = off[wid] + q;
    for (; e + 4 < end; e += 8) {
        int s0 = srcs[e], s1 = srcs[e + 4];
        half8 v0 = *(const half8*)(x + (size_t)s0 * 128 + fb);
        half8 v1 = *(const half8*)(x + (size_t)s1 * 128 + fb);
#pragma unroll
        for (int k = 0; k < 8; ++k) acc[k] += (float)v0[k] + (float)v1[k];
    }
    if (e < end) {
        int s0 = srcs[e];
        half8 v0 = *(const half8*)(x + (size_t)s0 * 128 + fb);
#pragma unroll
        for (int k = 0; k < 8; ++k) acc[k] += (float)v0[k];
    }
    if (q == 0) {                            // self term
        half8 v = *(const half8*)(x + (size_t)wid * 128 + fb);
#pragma unroll
        for (int k = 0; k < 8; ++k) acc[k] += (float)v[k];
    }
#pragma unroll
    for (int k = 0; k < 8; ++k) {
        acc[k] += __shfl_xor(acc[k], 16);
        acc[k] += __shfl_xor(acc[k], 32);
    }
    if (q == 0) {
        half8 o;
#pragma unroll
        for (int k = 0; k < 8; ++k) o[k] = (_Float16)acc[k];
        *(half8*)(out + (size_t)wid * 128 + fb) = o;
    }
}

// recurrent: reads PRE-norm z, BN affine + ReLU in packed fp16 (pk_fma/pk_max),
// f32 accumulate; 4 edges in flight per half-wave.
__global__ void gather_fused(const _Float16* __restrict__ z, const int* __restrict__ off,
                             const int* __restrict__ srcs, const float* __restrict__ stats,
                             const float* __restrict__ gam, const float* __restrict__ bet,
                             _Float16* __restrict__ out, int N, float invN) {
    int wid = (blockIdx.x << 2) + (threadIdx.x >> 6);
    if (wid >= N) return;
    int lane = threadIdx.x & 63;
    int hf = lane >> 5;
    int fb = (lane & 31) << 3;               // 8 fp16, 256 feats
    half8 sc8, tc8;
#pragma unroll
    for (int k = 0; k < 8; ++k) {
        float mu = stats[fb + k] * invN;
        float var = stats[256 + fb + k] * invN - mu * mu;
        float s = gam[fb + k] * rsqrtf(var + BN_EPS);
        sc8[k] = (_Float16)s;
        tc8[k] = (_Float16)(bet[fb + k] - mu * s);
    }
    const half8 zero8 = {0, 0, 0, 0, 0, 0, 0, 0};
    float acc[8] = {0.f, 0.f, 0.f, 0.f, 0.f, 0.f, 0.f, 0.f};
    int end = off[wid + 1];
    int e = off[wid] + hf;
    for (; e + 6 < end; e += 8) {
        int s0 = srcs[e], s1 = srcs[e + 2], s2 = srcs[e + 4], s3 = srcs[e + 6];
        half8 v0 = *(const half8*)(z + (size_t)s0 * 256 + fb);
        half8 v1 = *(const half8*)(z + (size_t)s1 * 256 + fb);
        half8 v2 = *(const half8*)(z + (size_t)s2 * 256 + fb);
        half8 v3 = *(const half8*)(z + (size_t)s3 * 256 + fb);
        half8 r0 = __builtin_elementwise_max(v0 * sc8 + tc8, zero8);
        half8 r1 = __builtin_elementwise_max(v1 * sc8 + tc8, zero8);
        half8 r2 = __builtin_elementwise_max(v2 * sc8 + tc8, zero8);
        half8 r3 = __builtin_elementwise_max(v3 * sc8 + tc8, zero8);
#pragma unroll
        for (int k = 0; k < 8; ++k)
            acc[k] += ((float)r0[k] + (float)r1[k]) + ((float)r2[k] + (float)r3[k]);
    }
    for (; e < end; e += 2) {
        int s0 = srcs[e];
        half8 v0 = *(const half8*)(z + (size_t)s0 * 256 + fb);
        half8 r0 = __builtin_elementwise_max(v0 * sc8 + tc8, zero8);
#pragma unroll
        for (int k = 0; k < 8; ++k) acc[k] += (float)r0[k];
    }
    if (hf == 0) {                           // self term
        half8 v = *(const half8*)(z + (size_t)wid * 256 + fb);
        half8 r = __builtin_elementwise_max(v * sc8 + tc8, zero8);
#pragma unroll
        for (int k = 0; k < 8; ++k) acc[k] += (float)r[k];
    }
#pragma unroll
    for (int k = 0; k < 8; ++k) acc[k] += __shfl_xor(acc[k], 32);
    if (hf == 0) {
        half8 o;
#pragma unroll
        for (int k = 0; k < 8; ++k) o[k] = (_Float16)acc[k];
        *(half8*)(out + (size_t)wid * 256 + fb) = o;
    }
}

// ---------------------------------------------------------------- fused MLP
// One block = 256 rows (16 waves x 16), full 256 cols. grid=196 -> 1 block/CU.
// Stage1: W1T in LDS (swizzled) -> y = relu(A@W1+b1) written fp16 to LDS
// (same region, row-XOR swizzle). Stage2: z = y@W2+b2 with W2T streamed from
// global (L2-hot); fp16 Z out + block-reduced BN stats (1 atomic/col/block).
template <int K1>
__global__ __launch_bounds__(1024) void mlp_fused(
    const _Float16* __restrict__ A, const _Float16* __restrict__ W1T,
    const float* __restrict__ b1, const _Float16* __restrict__ W2T,
    const float* __restrict__ b2, _Float16* __restrict__ Z,
    float* __restrict__ stats, int M) {
    extern __shared__ _Float16 lds[];        // 128 KiB
    const int tid = threadIdx.x;
    const int lane = tid & 63, wave = tid >> 6;
    const int i = lane & 15, g = lane >> 4;
    const int rowbase = blockIdx.x * 256 + wave * 16;
    const int arow = min(rowbase + i, M - 1);

    half8 afrag[K1 / 32];
#pragma unroll
    for (int s = 0; s < K1 / 32; ++s)
        afrag[s] = *(const half8*)(A + (size_t)arow * K1 + s * 32 + g * 8);

    {   // stage W1T [256][K1] fp16, k-chunks XOR-swizzled by row
        int row = tid >> 2, q = tid & 3, kq = q * (K1 / 4);
        const _Float16* src = W1T + (size_t)row * K1 + kq;
        _Float16* dst = lds + row * K1;
        int sw = (row & 7) << 3;
#pragma unroll
        for (int c = 0; c < K1 / 4; c += 8)
            *(half8*)(dst + ((kq + c) ^ sw)) = *(const half8*)(src + c);
    }
    __syncthreads();

    const int swi = (i & 7) << 3;
    f32x4 acc[16];
#pragma unroll
    for (int t = 0; t < 16; ++t) acc[t] = (f32x4){0.f, 0.f, 0.f, 0.f};
#pragma unroll
    for (int t = 0; t < 16; ++t)
#pragma unroll
        for (int s = 0; s < K1 / 32; ++s) {
            half8 b = *(const half8*)(lds + (t * 16 + i) * K1 + ((s * 32 + g * 8) ^ swi));
            acc[t] = __builtin_amdgcn_mfma_f32_16x16x32_f16(afrag[s], b, acc[t], 0, 0, 0);
        }
    __syncthreads();                         // all waves done reading W1T

    // y = relu(acc + b1) -> LDS [256 rows][256 cols] fp16, col ^ ((row&7)<<3)
#pragma unroll
    for (int t = 0; t < 16; ++t) {
        int c = t * 16 + i;
        float bv = b1[c];
#pragma unroll
        for (int j = 0; j < 4; ++j) {
            int r = wave * 16 + g * 4 + j;
            lds[r * 256 + (c ^ ((r & 7) << 3))] = (_Float16)fmaxf(acc[t][j] + bv, 0.f);
        }
    }
    __syncthreads();

    // stage 2: z = y @ W2 (+b2)
#pragma unroll
    for (int t = 0; t < 16; ++t) acc[t] = (f32x4){0.f, 0.f, 0.f, 0.f};
    const int yrow = wave * 16 + i;          // (yrow&7) == (i&7) -> swi
#pragma unroll
    for (int s = 0; s < 8; ++s) {
        half8 yf = *(const half8*)(lds + yrow * 256 + ((s * 32 + g * 8) ^ swi));
#pragma unroll
        for (int t = 0; t < 16; ++t) {
            half8 wf = *(const half8*)(W2T + (size_t)(t * 16 + i) * 256 + s * 32 + g * 8);
            acc[t] = __builtin_amdgcn_mfma_f32_16x16x32_f16(yf, wf, acc[t], 0, 0, 0);
        }
    }
    __syncthreads();                         // before reusing LDS as sred

    float* sred = (float*)lds;               // [2][16 waves][256 cols]
#pragma unroll
    for (int t = 0; t < 16; ++t) {
        int c = t * 16 + i;
        float bv = b2[c];
        float s1 = 0.f, s2 = 0.f;
#pragma unroll
        for (int j = 0; j < 4; ++j) {
            int r = rowbase + g * 4 + j;
            if (r < M) {
                float v = acc[t][j] + bv;
                Z[(size_t)r * 256 + c] = (_Float16)v;
                s1 += v;
                s2 += v * v;
            }
        }
        s1 += __shfl_xor(s1, 16); s1 += __shfl_xor(s1, 32);
        s2 += __shfl_xor(s2, 16); s2 += __shfl_xor(s2, 32);
        if (g == 0) {
            sred[wave * 256 + c] = s1;
            sred[4096 + wave * 256 + c] = s2;
        }
    }
    __syncthreads();
    if (tid < 512) {                         // one atomic per column per block
        int which = tid >> 8, c = tid & 255;
        float s = 0.f;
#pragma unroll
        for (int w = 0; w < 16; ++w) s += sred[which * 4096 + w * 256 + c];
        atomicAdd(&stats[which * 256 + c], s);
    }
}

// ---------------------------------------------------------------- pooling
__global__ void graph_bounds(const int* __restrict__ batch, int* __restrict__ gstart, int N) {
    int t = threadIdx.x;
    if (t > NGRAPH) return;
    if (t == NGRAPH) { gstart[t] = N; return; }
    int lo = 0, hi = N;
    while (lo < hi) { int m = (lo + hi) >> 1; if (batch[m] < t) lo = m + 1; else hi = m; }
    gstart[t] = lo;
}

#define PCHUNK 256
__global__ void pool_stage1(const _Float16* __restrict__ z, const int* __restrict__ batch,
                            const int* __restrict__ gstart, const float* __restrict__ stats,
                            const float* __restrict__ gam, const float* __restrict__ bet,
                            float* __restrict__ acc, int N, float invN) {
    __shared__ float lds[8 * 512];
    int c0 = blockIdx.x * PCHUNK;
    int cend = min(c0 + PCHUNK, N);
    int tid = threadIdx.x;
    int rowlane = tid >> 5;
    int fb = (tid & 31) << 3;
    float sc[8], tc[8];
#pragma unroll
    for (int k = 0; k < 8; ++k) {
        float mu = stats[fb + k] * invN;
        float var = stats[256 + fb + k] * invN - mu * mu;
        float s = gam[fb + k] * rsqrtf(var + BN_EPS);
        sc[k] = s;
        tc[k] = bet[fb + k] - mu * s;
    }
    int segs = c0;
    while (segs < cend) {
        int g = batch[segs];
        int sege = min(gstart[g + 1], cend);
        float a[8] = {0.f, 0.f, 0.f, 0.f, 0.f, 0.f, 0.f, 0.f};
        for (int r = segs + rowlane; r < sege; r += 16) {
            half8 v = *(const half8*)(z + (size_t)r * 256 + fb);
#pragma unroll
            for (int k = 0; k < 8; ++k)
                a[k] += fmaxf(fmaf((float)v[k], sc[k], tc[k]), 0.f);
        }
#pragma unroll
        for (int k = 0; k < 8; ++k) lds[k * 512 + tid] = a[k];
        __syncthreads();
#pragma unroll
        for (int d = 8; d > 0; d >>= 1) {
            if (rowlane < d) {
#pragma unroll
                for (int k = 0; k < 8; ++k)
                    lds[k * 512 + tid] += lds[k * 512 + tid + d * 32];
            }
            __syncthreads();
        }
        if (rowlane == 0) {
#pragma unroll
            for (int k = 0; k < 8; ++k)
                atomicAdd(&acc[g * 256 + fb + k], lds[k * 512 + tid]);
        }
        __syncthreads();
        segs = sege;
    }
}

__global__ void pool_finalize(const float* __restrict__ acc, const int* __restrict__ gstart,
                              float* __restrict__ out) {
    int i = blockIdx.x * 256 + threadIdx.x;
    int g = i >> 8;
    int c = gstart[g + 1] - gstart[g];
    out[i] = acc[i] / (float)(c > 0 ? c : 1);
}

// ---------------------------------------------------------------- launch
extern "C" void kernel_launch(void* const* d_in, const int* in_sizes, int n_in,
                              void* d_out, int out_size, void* d_ws, size_t ws_size,
                              hipStream_t stream) {
    const float* x    = (const float*)d_in[0];
    const int*   ei   = (const int*)d_in[1];
    const int*   batch= (const int*)d_in[2];
    const float* w1_0 = (const float*)d_in[3];
    const float* b1_0 = (const float*)d_in[4];
    const float* w2_0 = (const float*)d_in[5];
    const float* b2_0 = (const float*)d_in[6];
    const float* g_0  = (const float*)d_in[7];
    const float* be_0 = (const float*)d_in[8];
    const float* w1_r = (const float*)d_in[9];
    const float* b1_r = (const float*)d_in[10];
    const float* w2_r = (const float*)d_in[11];
    const float* b2_r = (const float*)d_in[12];
    const float* g_r  = (const float*)d_in[13];
    const float* be_r = (const float*)d_in[14];

    const int N = in_sizes[0] / 128;   // 50000
    const int E = in_sizes[1] / 2;     // 800000

    // workspace carve (256B aligned)
    char* p = (char*)d_ws;
    auto alloc = [&](size_t bytes) { char* r = p; p += (bytes + 255) & ~(size_t)255; return r; };
    float*    stats   = (float*)alloc(4 * 512 * sizeof(float));
    int*      part    = (int*)alloc(256 * sizeof(int));
    int*      off     = (int*)alloc((size_t)(N + 1) * sizeof(int));
    int*      cnt     = (int*)alloc((size_t)N * sizeof(int));
    int*      gstart  = (int*)alloc(65 * sizeof(int));
    float*    accp    = (float*)alloc(NGRAPH * 256 * sizeof(float));
    int*      rank    = (int*)alloc((size_t)E * sizeof(int));
    int*      csr_src = (int*)alloc((size_t)E * sizeof(int));
    _Float16* wT      = (_Float16*)alloc((size_t)491520 * sizeof(_Float16));
    _Float16* x16     = (_Float16*)alloc((size_t)N * 128 * sizeof(_Float16));
    _Float16* zin     = (_Float16*)alloc((size_t)N * 256 * sizeof(_Float16));
    _Float16* z       = (_Float16*)alloc((size_t)N * 256 * sizeof(_Float16));

    hipMemsetAsync(stats, 0, 4 * 512 * sizeof(float), stream);
    hipMemsetAsync(cnt, 0, (size_t)N * sizeof(int), stream);
    hipMemsetAsync(accp, 0, NGRAPH * 256 * sizeof(float), stream);

    // transpose all weights to fp16 [256][K]
    PrepArgs pa;
    pa.src[0] = w1_0;  pa.dst[0] = wT;           pa.K[0] = 128;
    pa.src[1] = w2_0;  pa.dst[1] = wT + 32768;   pa.K[1] = 256;
    for (int i = 0; i < 3; ++i) {
        pa.src[2 + i] = w1_r + (size_t)i * 65536; pa.dst[2 + i] = wT + 98304 + (size_t)i * 65536; pa.K[2 + i] = 256;
        pa.src[5 + i] = w2_r + (size_t)i * 65536; pa.dst[5 + i] = wT + 294912 + (size_t)i * 65536; pa.K[5 + i] = 256;
    }
    prep_weights<<<dim3(256, 8), 256, 0, stream>>>(pa);
    cast_x<<<(N * 128 / 8 + 255) / 256, 256, 0, stream>>>(x, x16, N * 128);

    const int eb = (E + 255) / 256;
    const int nb = (N + 255) / 256;
    edge_count<<<eb, 256, 0, stream>>>(ei, cnt, rank, E);
    scan_p1<<<nb, 256, 0, stream>>>(cnt, part, N);
    scan_p2<<<1, 256, 0, stream>>>(part, off, N, nb);
    scan_p3<<<nb, 256, 0, stream>>>(cnt, part, off, N);
    edge_fill<<<eb, 256, 0, stream>>>(ei, off, rank, csr_src, E);
    graph_bounds<<<1, 128, 0, stream>>>(batch, gstart, N);

    const int gwb = (N + 3) / 4;               // gather blocks (4 waves each)
    const int mlpg = (N + 255) / 256;          // 196 blocks, 1 per CU
    const float invN = 1.0f / (float)N;

    // ---- layer 0
    gather0<<<gwb, 256, 0, stream>>>(x16, off, csr_src, zin, N);
    mlp_fused<128><<<mlpg, 1024, 131072, stream>>>(zin, wT, b1_0, wT + 32768, b2_0, z, stats, N);

    // ---- layers 1..3 (BN of previous layer fused into gather)
    const float* cur_stats = stats;
    const float* cur_g = g_0;
    const float* cur_be = be_0;
    for (int i = 0; i < 3; ++i) {
        gather_fused<<<gwb, 256, 0, stream>>>(z, off, csr_src, cur_stats, cur_g, cur_be, zin, N, invN);
        mlp_fused<256><<<mlpg, 1024, 131072, stream>>>(
            zin, wT + 98304 + (size_t)i * 65536, b1_r + i * 256,
            wT + 294912 + (size_t)i * 65536, b2_r + i * 256, z, stats + (i + 1) * 512, N);
        cur_stats = stats + (i + 1) * 512;
        cur_g = g_r + i * 256;
        cur_be = be_r + i * 256;
    }

    // ---- pool (BN of last layer fused)
    pool_stage1<<<(N + PCHUNK - 1) / PCHUNK, 512, 0, stream>>>(
        z, batch, gstart, cur_stats, cur_g, cur_be, accp, N, invN);
    pool_finalize<<<NGRAPH, 256, 0, stream>>>(accp, gstart, (float*)d_out);
}

// Round 7
// 525.371 us; speedup vs baseline: 1.2529x; 1.2529x over previous
//
#include <hip/hip_runtime.h>

typedef float  f32x4 __attribute__((ext_vector_type(4)));
typedef _Float16 half8 __attribute__((ext_vector_type(8)));
typedef _Float16 half4 __attribute__((ext_vector_type(4)));

#define BN_EPS 1e-5f
#define NGRAPH 64

// ---------------------------------------------------------------- weights prep
struct PrepArgs {
    const float* src[8];
    _Float16*    dst[8];
    int          K[8];
};

// transpose [K][256] f32 -> [256][K] fp16, dst-major (coalesced writes)
__global__ void prep_weights(PrepArgs a) {
    int m = blockIdx.y;
    int K = a.K[m];
    int total = K << 8;
    int idx = blockIdx.x * blockDim.x + threadIdx.x;
    if (idx >= total) return;
    int n = idx / K;
    int k = idx - n * K;
    a.dst[m][idx] = (_Float16)a.src[m][(size_t)k * 256 + n];
}

__global__ void cast_x(const float* __restrict__ x, _Float16* __restrict__ o, int total) {
    int i = (blockIdx.x * blockDim.x + threadIdx.x) << 3;
    if (i >= total) return;
    f32x4 a = *(const f32x4*)(x + i);
    f32x4 b = *(const f32x4*)(x + i + 4);
    half8 r;
#pragma unroll
    for (int k = 0; k < 4; ++k) { r[k] = (_Float16)a[k]; r[k + 4] = (_Float16)b[k]; }
    *(half8*)(o + i) = r;
}

// ---------------------------------------------------------------- CSR build
// count + rank in one pass: rank[e] = position of edge e within its dst segment.
__global__ void edge_count(const int* __restrict__ ei, int* __restrict__ cnt,
                           int* __restrict__ rank, int E) {
    int e = blockIdx.x * blockDim.x + threadIdx.x;
    if (e < E) rank[e] = atomicAdd(&cnt[ei[E + e]], 1);
}

__global__ void scan_p1(const int* __restrict__ cnt, int* __restrict__ part, int N) {
    __shared__ int lds[256];
    int idx = blockIdx.x * 256 + threadIdx.x;
    lds[threadIdx.x] = (idx < N) ? cnt[idx] : 0;
    __syncthreads();
    for (int d = 128; d > 0; d >>= 1) {
        if (threadIdx.x < d) lds[threadIdx.x] += lds[threadIdx.x + d];
        __syncthreads();
    }
    if (threadIdx.x == 0) part[blockIdx.x] = lds[0];
}

__global__ void scan_p2(int* __restrict__ part, int* __restrict__ off, int N, int nb) {
    __shared__ int lds[256];
    int t = threadIdx.x;
    int v = (t < nb) ? part[t] : 0;
    lds[t] = v;
    __syncthreads();
    for (int d = 1; d < 256; d <<= 1) {
        int a = (t >= d) ? lds[t - d] : 0;
        __syncthreads();
        lds[t] += a;
        __syncthreads();
    }
    if (t < nb) part[t] = lds[t] - v;       // exclusive
    if (t == nb - 1) off[N] = lds[t];       // total = E
}

__global__ void scan_p3(const int* __restrict__ cnt, const int* __restrict__ part,
                        int* __restrict__ off, int N) {
    __shared__ int lds[256];
    int t = threadIdx.x;
    int idx = blockIdx.x * 256 + t;
    int v = (idx < N) ? cnt[idx] : 0;
    lds[t] = v;
    __syncthreads();
    for (int d = 1; d < 256; d <<= 1) {
        int a = (t >= d) ? lds[t - d] : 0;
        __syncthreads();
        lds[t] += a;
        __syncthreads();
    }
    if (idx < N) off[idx] = part[blockIdx.x] + lds[t] - v;
}

// atomic-free fill: slot = off[dst] + rank
__global__ void edge_fill(const int* __restrict__ ei, const int* __restrict__ off,
                          const int* __restrict__ rank, int* __restrict__ csr_src, int E) {
    int e = blockIdx.x * blockDim.x + threadIdx.x;
    if (e >= E) return;
    csr_src[off[ei[E + e]] + rank[e]] = ei[e];
}

// ---------------------------------------------------------------- gathers
// layer 0: fp16 x, 128 feats -> quarter-wave per row, 8 row-loads in flight/wave
__global__ void gather0(const _Float16* __restrict__ x, const int* __restrict__ off,
                        const int* __restrict__ srcs, _Float16* __restrict__ out, int N) {
    int wid = (blockIdx.x << 2) + (threadIdx.x >> 6);
    if (wid >= N) return;
    int lane = threadIdx.x & 63;
    int q = lane >> 4;
    int fb = (lane & 15) << 3;               // 8 fp16, 128 feats
    float acc[8] = {0.f, 0.f, 0.f, 0.f, 0.f, 0.f, 0.f, 0.f};
    int end = off[wid + 1];
    int e = off[wid] + q;
    for (; e + 4 < end; e += 8) {
        int s0 = srcs[e], s1 = srcs[e + 4];
        half8 v0 = *(const half8*)(x + (size_t)s0 * 128 + fb);
        half8 v1 = *(const half8*)(x + (size_t)s1 * 128 + fb);
#pragma unroll
        for (int k = 0; k < 8; ++k) acc[k] += (float)v0[k] + (float)v1[k];
    }
    if (e < end) {
        int s0 = srcs[e];
        half8 v0 = *(const half8*)(x + (size_t)s0 * 128 + fb);
#pragma unroll
        for (int k = 0; k < 8; ++k) acc[k] += (float)v0[k];
    }
    if (q == 0) {                            // self term
        half8 v = *(const half8*)(x + (size_t)wid * 128 + fb);
#pragma unroll
        for (int k = 0; k < 8; ++k) acc[k] += (float)v[k];
    }
#pragma unroll
    for (int k = 0; k < 8; ++k) {
        acc[k] += __shfl_xor(acc[k], 16);
        acc[k] += __shfl_xor(acc[k], 32);
    }
    if (q == 0) {
        half8 o;
#pragma unroll
        for (int k = 0; k < 8; ++k) o[k] = (_Float16)acc[k];
        *(half8*)(out + (size_t)wid * 128 + fb) = o;
    }
}

// recurrent: reads PRE-norm z, BN affine + ReLU in packed fp16,
// f32 accumulate; 4 edges in flight per half-wave.
__global__ void gather_fused(const _Float16* __restrict__ z, const int* __restrict__ off,
                             const int* __restrict__ srcs, const float* __restrict__ stats,
                             const float* __restrict__ gam, const float* __restrict__ bet,
                             _Float16* __restrict__ out, int N, float invN) {
    int wid = (blockIdx.x << 2) + (threadIdx.x >> 6);
    if (wid >= N) return;
    int lane = threadIdx.x & 63;
    int hf = lane >> 5;
    int fb = (lane & 31) << 3;               // 8 fp16, 256 feats
    half8 sc8, tc8;
#pragma unroll
    for (int k = 0; k < 8; ++k) {
        float mu = stats[fb + k] * invN;
        float var = stats[256 + fb + k] * invN - mu * mu;
        float s = gam[fb + k] * rsqrtf(var + BN_EPS);
        sc8[k] = (_Float16)s;
        tc8[k] = (_Float16)(bet[fb + k] - mu * s);
    }
    const half8 zero8 = {0, 0, 0, 0, 0, 0, 0, 0};
    float acc[8] = {0.f, 0.f, 0.f, 0.f, 0.f, 0.f, 0.f, 0.f};
    int end = off[wid + 1];
    int e = off[wid] + hf;
    for (; e + 6 < end; e += 8) {
        int s0 = srcs[e], s1 = srcs[e + 2], s2 = srcs[e + 4], s3 = srcs[e + 6];
        half8 v0 = *(const half8*)(z + (size_t)s0 * 256 + fb);
        half8 v1 = *(const half8*)(z + (size_t)s1 * 256 + fb);
        half8 v2 = *(const half8*)(z + (size_t)s2 * 256 + fb);
        half8 v3 = *(const half8*)(z + (size_t)s3 * 256 + fb);
        half8 r0 = __builtin_elementwise_max(v0 * sc8 + tc8, zero8);
        half8 r1 = __builtin_elementwise_max(v1 * sc8 + tc8, zero8);
        half8 r2 = __builtin_elementwise_max(v2 * sc8 + tc8, zero8);
        half8 r3 = __builtin_elementwise_max(v3 * sc8 + tc8, zero8);
#pragma unroll
        for (int k = 0; k < 8; ++k)
            acc[k] += ((float)r0[k] + (float)r1[k]) + ((float)r2[k] + (float)r3[k]);
    }
    for (; e < end; e += 2) {
        int s0 = srcs[e];
        half8 v0 = *(const half8*)(z + (size_t)s0 * 256 + fb);
        half8 r0 = __builtin_elementwise_max(v0 * sc8 + tc8, zero8);
#pragma unroll
        for (int k = 0; k < 8; ++k) acc[k] += (float)r0[k];
    }
    if (hf == 0) {                           // self term
        half8 v = *(const half8*)(z + (size_t)wid * 256 + fb);
        half8 r = __builtin_elementwise_max(v * sc8 + tc8, zero8);
#pragma unroll
        for (int k = 0; k < 8; ++k) acc[k] += (float)r[k];
    }
#pragma unroll
    for (int k = 0; k < 8; ++k) acc[k] += __shfl_xor(acc[k], 32);
    if (hf == 0) {
        half8 o;
#pragma unroll
        for (int k = 0; k < 8; ++k) o[k] = (_Float16)acc[k];
        *(half8*)(out + (size_t)wid * 256 + fb) = o;
    }
}

// ---------------------------------------------------------------- GEMM (fp16 MFMA)
// C[M,256] = A[M,K] @ W[K,256] (+bias). BT = W^T [256][K] fp16.
// BM=128 (8 waves x 16 rows), BN=128 (blockIdx.y half), T2 XOR-swizzled LDS.
// Epilogue stages the 128x128 output tile in LDS (reusing the weight region,
// +8 fp16 row pad) so global stores are half8 fully coalesced.
// Round-7 fix: chunk loop is 4*512 (=2048 chunks of 8), NOT 8*512 — the 8x
// version read past the staged tile and clobbered neighbor blocks' rows.
// WITH_STATS: no ReLU, block-reduced column sum/sumsq, 1 atomic/col/block.
template <int K, int WITH_STATS>
__global__ __launch_bounds__(512, 2) void gemm_kernel(
    const _Float16* __restrict__ A, const _Float16* __restrict__ BT,
    const float* __restrict__ bias, _Float16* __restrict__ Y,
    float* __restrict__ stats, int M) {
    extern __shared__ _Float16 blds[];      // weights [128][K] swz; later ostage+sred
    const int tid = threadIdx.x;
    const int colbase = blockIdx.y * 128;
    {
        int row = tid >> 2, q = tid & 3, kq = q * (K / 4);
        const _Float16* src = BT + (size_t)(colbase + row) * K + kq;
        _Float16* dst = blds + row * K;
        int sw = (row & 7) << 3;
#pragma unroll
        for (int c = 0; c < K / 4; c += 8)
            *(half8*)(dst + ((kq + c) ^ sw)) = *(const half8*)(src + c);
    }
    __syncthreads();

    const int lane = tid & 63, wave = tid >> 6;
    const int i = lane & 15, g = lane >> 4;
    const int rowbase = blockIdx.x * 128 + wave * 16;
    const int arow = min(rowbase + i, M - 1);

    half8 afrag[K / 32];
#pragma unroll
    for (int s = 0; s < K / 32; ++s)
        afrag[s] = *(const half8*)(A + (size_t)arow * K + s * 32 + g * 8);

    f32x4 acc[8];
#pragma unroll
    for (int t = 0; t < 8; ++t) acc[t] = (f32x4){0.f, 0.f, 0.f, 0.f};

    const int sw = (i & 7) << 3;
#pragma unroll
    for (int s = 0; s < K / 32; ++s)
#pragma unroll
        for (int t = 0; t < 8; ++t) {
            half8 b = *(const half8*)(blds + (t * 16 + i) * K + ((s * 32 + g * 8) ^ sw));
            acc[t] = __builtin_amdgcn_mfma_f32_16x16x32_f16(afrag[s], b, acc[t], 0, 0, 0);
        }
    __syncthreads();                         // weights dead; reuse LDS

    _Float16* ostage = blds;                 // [128][136] fp16 (pad 8: <=2-way banks)
    float* sred = (float*)(blds + 17408);    // byte 34816: [2][8 waves][128 cols]
    const int rg = g * 4;
#pragma unroll
    for (int t = 0; t < 8; ++t) {
        int c = t * 16 + i;
        float bv = bias[colbase + c];
        float s1 = 0.f, s2 = 0.f;
#pragma unroll
        for (int j = 0; j < 4; ++j) {
            float v = acc[t][j] + bv;
            if (WITH_STATS == 0) v = fmaxf(v, 0.f);
            ostage[(wave * 16 + rg + j) * 136 + c] = (_Float16)v;
            if (WITH_STATS) {
                if (rowbase + rg + j < M) { s1 += v; s2 += v * v; }
            }
        }
        if (WITH_STATS) {
            s1 += __shfl_xor(s1, 16); s1 += __shfl_xor(s1, 32);
            s2 += __shfl_xor(s2, 16); s2 += __shfl_xor(s2, 32);
            if (g == 0) {
                sred[wave * 128 + c] = s1;
                sred[1024 + wave * 128 + c] = s2;
            }
        }
    }
    __syncthreads();
    if (WITH_STATS && tid < 256) {           // one atomic per column per block
        int which = tid >> 7, c = tid & 127;
        float s = 0.f;
#pragma unroll
        for (int w = 0; w < 8; ++w) s += sred[which * 1024 + w * 128 + c];
        atomicAdd(&stats[which * 256 + colbase + c], s);
    }
    // coalesced store: 2048 half8 chunks (128 rows x 16), 4 per thread
#pragma unroll
    for (int k = 0; k < 4; ++k) {
        int ch = k * 512 + tid;
        int rl = ch >> 4, pc = (ch & 15) << 3;
        int r = blockIdx.x * 128 + rl;
        if (r < M)
            *(half8*)(Y + (size_t)r * 256 + colbase + pc) =
                *(const half8*)(ostage + rl * 136 + pc);
    }
}

// ---------------------------------------------------------------- pooling
__global__ void graph_bounds(const int* __restrict__ batch, int* __restrict__ gstart, int N) {
    int t = threadIdx.x;
    if (t > NGRAPH) return;
    if (t == NGRAPH) { gstart[t] = N; return; }
    int lo = 0, hi = N;
    while (lo < hi) { int m = (lo + hi) >> 1; if (batch[m] < t) lo = m + 1; else hi = m; }
    gstart[t] = lo;
}

#define PCHUNK 256
__global__ void pool_stage1(const _Float16* __restrict__ z, const int* __restrict__ batch,
                            const int* __restrict__ gstart, const float* __restrict__ stats,
                            const float* __restrict__ gam, const float* __restrict__ bet,
                            float* __restrict__ acc, int N, float invN) {
    __shared__ float lds[8 * 512];
    int c0 = blockIdx.x * PCHUNK;
    int cend = min(c0 + PCHUNK, N);
    int tid = threadIdx.x;
    int rowlane = tid >> 5;
    int fb = (tid & 31) << 3;
    float sc[8], tc[8];
#pragma unroll
    for (int k = 0; k < 8; ++k) {
        float mu = stats[fb + k] * invN;
        float var = stats[256 + fb + k] * invN - mu * mu;
        float s = gam[fb + k] * rsqrtf(var + BN_EPS);
        sc[k] = s;
        tc[k] = bet[fb + k] - mu * s;
    }
    int segs = c0;
    while (segs < cend) {
        int g = batch[segs];
        int sege = min(gstart[g + 1], cend);
        float a[8] = {0.f, 0.f, 0.f, 0.f, 0.f, 0.f, 0.f, 0.f};
        for (int r = segs + rowlane; r < sege; r += 16) {
            half8 v = *(const half8*)(z + (size_t)r * 256 + fb);
#pragma unroll
            for (int k = 0; k < 8; ++k)
                a[k] += fmaxf(fmaf((float)v[k], sc[k], tc[k]), 0.f);
        }
#pragma unroll
        for (int k = 0; k < 8; ++k) lds[k * 512 + tid] = a[k];
        __syncthreads();
#pragma unroll
        for (int d = 8; d > 0; d >>= 1) {
            if (rowlane < d) {
#pragma unroll
                for (int k = 0; k < 8; ++k)
                    lds[k * 512 + tid] += lds[k * 512 + tid + d * 32];
            }
            __syncthreads();
        }
        if (rowlane == 0) {
#pragma unroll
            for (int k = 0; k < 8; ++k)
                atomicAdd(&acc[g * 256 + fb + k], lds[k * 512 + tid]);
        }
        __syncthreads();
        segs = sege;
    }
}

__global__ void pool_finalize(const float* __restrict__ acc, const int* __restrict__ gstart,
                              float* __restrict__ out) {
    int i = blockIdx.x * 256 + threadIdx.x;
    int g = i >> 8;
    int c = gstart[g + 1] - gstart[g];
    out[i] = acc[i] / (float)(c > 0 ? c : 1);
}

// ---------------------------------------------------------------- launch
extern "C" void kernel_launch(void* const* d_in, const int* in_sizes, int n_in,
                              void* d_out, int out_size, void* d_ws, size_t ws_size,
                              hipStream_t stream) {
    const float* x    = (const float*)d_in[0];
    const int*   ei   = (const int*)d_in[1];
    const int*   batch= (const int*)d_in[2];
    const float* w1_0 = (const float*)d_in[3];
    const float* b1_0 = (const float*)d_in[4];
    const float* w2_0 = (const float*)d_in[5];
    const float* b2_0 = (const float*)d_in[6];
    const float* g_0  = (const float*)d_in[7];
    const float* be_0 = (const float*)d_in[8];
    const float* w1_r = (const float*)d_in[9];
    const float* b1_r = (const float*)d_in[10];
    const float* w2_r = (const float*)d_in[11];
    const float* b2_r = (const float*)d_in[12];
    const float* g_r  = (const float*)d_in[13];
    const float* be_r = (const float*)d_in[14];

    const int N = in_sizes[0] / 128;   // 50000
    const int E = in_sizes[1] / 2;     // 800000

    // workspace carve (256B aligned)
    char* p = (char*)d_ws;
    auto alloc = [&](size_t bytes) { char* r = p; p += (bytes + 255) & ~(size_t)255; return r; };
    float*    stats   = (float*)alloc(4 * 512 * sizeof(float));
    int*      part    = (int*)alloc(256 * sizeof(int));
    int*      off     = (int*)alloc((size_t)(N + 1) * sizeof(int));
    int*      cnt     = (int*)alloc((size_t)N * sizeof(int));
    int*      gstart  = (int*)alloc(65 * sizeof(int));
    float*    accp    = (float*)alloc(NGRAPH * 256 * sizeof(float));
    int*      rank    = (int*)alloc((size_t)E * sizeof(int));
    int*      csr_src = (int*)alloc((size_t)E * sizeof(int));
    _Float16* wT      = (_Float16*)alloc((size_t)491520 * sizeof(_Float16));
    _Float16* x16     = (_Float16*)alloc((size_t)N * 128 * sizeof(_Float16));
    _Float16* zin     = (_Float16*)alloc((size_t)N * 256 * sizeof(_Float16));
    _Float16* y       = (_Float16*)alloc((size_t)N * 256 * sizeof(_Float16));
    _Float16* z       = (_Float16*)alloc((size_t)N * 256 * sizeof(_Float16));

    hipMemsetAsync(stats, 0, 4 * 512 * sizeof(float), stream);
    hipMemsetAsync(cnt, 0, (size_t)N * sizeof(int), stream);
    hipMemsetAsync(accp, 0, NGRAPH * 256 * sizeof(float), stream);

    // transpose all weights to fp16 [256][K]
    PrepArgs pa;
    pa.src[0] = w1_0;  pa.dst[0] = wT;           pa.K[0] = 128;
    pa.src[1] = w2_0;  pa.dst[1] = wT + 32768;   pa.K[1] = 256;
    for (int i = 0; i < 3; ++i) {
        pa.src[2 + i] = w1_r + (size_t)i * 65536; pa.dst[2 + i] = wT + 98304 + (size_t)i * 65536; pa.K[2 + i] = 256;
        pa.src[5 + i] = w2_r + (size_t)i * 65536; pa.dst[5 + i] = wT + 294912 + (size_t)i * 65536; pa.K[5 + i] = 256;
    }
    prep_weights<<<dim3(256, 8), 256, 0, stream>>>(pa);
    cast_x<<<(N * 128 / 8 + 255) / 256, 256, 0, stream>>>(x, x16, N * 128);

    const int eb = (E + 255) / 256;
    const int nb = (N + 255) / 256;
    edge_count<<<eb, 256, 0, stream>>>(ei, cnt, rank, E);
    scan_p1<<<nb, 256, 0, stream>>>(cnt, part, N);
    scan_p2<<<1, 256, 0, stream>>>(part, off, N, nb);
    scan_p3<<<nb, 256, 0, stream>>>(cnt, part, off, N);
    edge_fill<<<eb, 256, 0, stream>>>(ei, off, rank, csr_src, E);
    graph_bounds<<<1, 128, 0, stream>>>(batch, gstart, N);

    const int gwb = (N + 3) / 4;               // gather blocks (4 waves each)
    const dim3 gemmg((N + 127) / 128, 2);
    const int lds128 = 43008;                  // max(weights 32KB, ostage+sred 42KB)
    const int lds256 = 65536;                  // weights 64KB > ostage+sred
    const float invN = 1.0f / (float)N;

    // ---- layer 0
    gather0<<<gwb, 256, 0, stream>>>(x16, off, csr_src, zin, N);
    gemm_kernel<128, 0><<<gemmg, 512, lds128, stream>>>(zin, wT, b1_0, y, nullptr, N);
    gemm_kernel<256, 1><<<gemmg, 512, lds256, stream>>>(y, wT + 32768, b2_0, z, stats, N);

    // ---- layers 1..3 (BN of previous layer fused into gather)
    const float* cur_stats = stats;
    const float* cur_g = g_0;
    const float* cur_be = be_0;
    for (int i = 0; i < 3; ++i) {
        gather_fused<<<gwb, 256, 0, stream>>>(z, off, csr_src, cur_stats, cur_g, cur_be, zin, N, invN);
        gemm_kernel<256, 0><<<gemmg, 512, lds256, stream>>>(
            zin, wT + 98304 + (size_t)i * 65536, b1_r + i * 256, y, nullptr, N);
        gemm_kernel<256, 1><<<gemmg, 512, lds256, stream>>>(
            y, wT + 294912 + (size_t)i * 65536, b2_r + i * 256, z, stats + (i + 1) * 512, N);
        cur_stats = stats + (i + 1) * 512;
        cur_g = g_r + i * 256;
        cur_be = be_r + i * 256;
    }

    // ---- pool (BN of last layer fused)
    pool_stage1<<<(N + PCHUNK - 1) / PCHUNK, 512, 0, stream>>>(
        z, batch, gstart, cur_stats, cur_g, cur_be, accp, N, invN);
    pool_finalize<<<NGRAPH, 256, 0, stream>>>(accp, gstart, (float*)d_out);
}

// Round 8
// 476.025 us; speedup vs baseline: 1.3828x; 1.1037x over previous
//
#include <hip/hip_runtime.h>

typedef float  f32x4 __attribute__((ext_vector_type(4)));
typedef _Float16 half8 __attribute__((ext_vector_type(8)));

#define BN_EPS 1e-5f
#define NGRAPH 64

// ---------------------------------------------------------------- weights prep
struct PrepArgs {
    const float* src[8];
    _Float16*    dst[8];
    int          K[8];
};

__global__ void prep_weights(PrepArgs a) {
    int m = blockIdx.y;
    int K = a.K[m];
    int total = K << 8;
    int idx = blockIdx.x * blockDim.x + threadIdx.x;
    if (idx >= total) return;
    int n = idx / K;
    int k = idx - n * K;
    a.dst[m][idx] = (_Float16)a.src[m][(size_t)k * 256 + n];
}

__global__ void cast_x(const float* __restrict__ x, _Float16* __restrict__ o, int total) {
    int i = (blockIdx.x * blockDim.x + threadIdx.x) << 3;
    if (i >= total) return;
    f32x4 a = *(const f32x4*)(x + i);
    f32x4 b = *(const f32x4*)(x + i + 4);
    half8 r;
#pragma unroll
    for (int k = 0; k < 4; ++k) { r[k] = (_Float16)a[k]; r[k + 4] = (_Float16)b[k]; }
    *(half8*)(o + i) = r;
}

// ---------------------------------------------------------------- CSR build
__global__ void edge_count(const int* __restrict__ ei, int* __restrict__ cnt,
                           int* __restrict__ rank, int E) {
    int e = blockIdx.x * blockDim.x + threadIdx.x;
    if (e < E) rank[e] = atomicAdd(&cnt[ei[E + e]], 1);
}

__global__ void scan_p1(const int* __restrict__ cnt, int* __restrict__ part, int N) {
    __shared__ int lds[256];
    int idx = blockIdx.x * 256 + threadIdx.x;
    lds[threadIdx.x] = (idx < N) ? cnt[idx] : 0;
    __syncthreads();
    for (int d = 128; d > 0; d >>= 1) {
        if (threadIdx.x < d) lds[threadIdx.x] += lds[threadIdx.x + d];
        __syncthreads();
    }
    if (threadIdx.x == 0) part[blockIdx.x] = lds[0];
}

__global__ void scan_p2(int* __restrict__ part, int* __restrict__ off, int N, int nb) {
    __shared__ int lds[256];
    int t = threadIdx.x;
    int v = (t < nb) ? part[t] : 0;
    lds[t] = v;
    __syncthreads();
    for (int d = 1; d < 256; d <<= 1) {
        int a = (t >= d) ? lds[t - d] : 0;
        __syncthreads();
        lds[t] += a;
        __syncthreads();
    }
    if (t < nb) part[t] = lds[t] - v;
    if (t == nb - 1) off[N] = lds[t];
}

__global__ void scan_p3(const int* __restrict__ cnt, const int* __restrict__ part,
                        int* __restrict__ off, int N) {
    __shared__ int lds[256];
    int t = threadIdx.x;
    int idx = blockIdx.x * 256 + t;
    int v = (idx < N) ? cnt[idx] : 0;
    lds[t] = v;
    __syncthreads();
    for (int d = 1; d < 256; d <<= 1) {
        int a = (t >= d) ? lds[t - d] : 0;
        __syncthreads();
        lds[t] += a;
        __syncthreads();
    }
    if (idx < N) off[idx] = part[blockIdx.x] + lds[t] - v;
}

__global__ void edge_fill(const int* __restrict__ ei, const int* __restrict__ off,
                          const int* __restrict__ rank, int* __restrict__ csr_src, int E) {
    int e = blockIdx.x * blockDim.x + threadIdx.x;
    if (e >= E) return;
    csr_src[off[ei[E + e]] + rank[e]] = ei[e];
}

// ---------------------------------------------------------------- gathers
// layer 0: fp16 x, 128 feats -> quarter-wave per row; 4-deep unroll per quarter.
__global__ void gather0(const _Float16* __restrict__ x, const int* __restrict__ off,
                        const int* __restrict__ srcs, _Float16* __restrict__ out, int N) {
    int wid = (blockIdx.x << 2) + (threadIdx.x >> 6);
    if (wid >= N) return;
    int lane = threadIdx.x & 63;
    int q = lane >> 4;
    int fb = (lane & 15) << 3;
    const char* xb = (const char*)x;
    float acc[8] = {0.f, 0.f, 0.f, 0.f, 0.f, 0.f, 0.f, 0.f};
    int end = off[wid + 1];
    int e = off[wid] + q;
    unsigned fb2 = (unsigned)fb << 1;
    for (; e + 12 < end; e += 16) {
        half8 v0 = *(const half8*)(xb + (((unsigned)srcs[e] << 8) + fb2));
        half8 v1 = *(const half8*)(xb + (((unsigned)srcs[e + 4] << 8) + fb2));
        half8 v2 = *(const half8*)(xb + (((unsigned)srcs[e + 8] << 8) + fb2));
        half8 v3 = *(const half8*)(xb + (((unsigned)srcs[e + 12] << 8) + fb2));
#pragma unroll
        for (int k = 0; k < 8; ++k)
            acc[k] += ((float)v0[k] + (float)v1[k]) + ((float)v2[k] + (float)v3[k]);
    }
    for (; e + 4 < end; e += 8) {
        half8 v0 = *(const half8*)(xb + (((unsigned)srcs[e] << 8) + fb2));
        half8 v1 = *(const half8*)(xb + (((unsigned)srcs[e + 4] << 8) + fb2));
#pragma unroll
        for (int k = 0; k < 8; ++k) acc[k] += (float)v0[k] + (float)v1[k];
    }
    if (e < end) {
        half8 v0 = *(const half8*)(xb + (((unsigned)srcs[e] << 8) + fb2));
#pragma unroll
        for (int k = 0; k < 8; ++k) acc[k] += (float)v0[k];
    }
    if (q == 0) {
        half8 v = *(const half8*)(xb + (((unsigned)wid << 8) + fb2));
#pragma unroll
        for (int k = 0; k < 8; ++k) acc[k] += (float)v[k];
    }
#pragma unroll
    for (int k = 0; k < 8; ++k) {
        acc[k] += __shfl_xor(acc[k], 16);
        acc[k] += __shfl_xor(acc[k], 32);
    }
    if (q == 0) {
        half8 o;
#pragma unroll
        for (int k = 0; k < 8; ++k) o[k] = (_Float16)acc[k];
        *(half8*)(out + (size_t)wid * 128 + fb) = o;
    }
}

// recurrent: PRE-norm z, BN affine + ReLU packed fp16; 8-deep unroll per half-wave.
__global__ void gather_fused(const _Float16* __restrict__ z, const int* __restrict__ off,
                             const int* __restrict__ srcs, const float* __restrict__ stats,
                             const float* __restrict__ gam, const float* __restrict__ bet,
                             _Float16* __restrict__ out, int N, float invN) {
    int wid = (blockIdx.x << 2) + (threadIdx.x >> 6);
    if (wid >= N) return;
    int lane = threadIdx.x & 63;
    int hf = lane >> 5;
    int fb = (lane & 31) << 3;
    half8 sc8, tc8;
#pragma unroll
    for (int k = 0; k < 8; ++k) {
        float mu = stats[fb + k] * invN;
        float var = stats[256 + fb + k] * invN - mu * mu;
        float s = gam[fb + k] * rsqrtf(var + BN_EPS);
        sc8[k] = (_Float16)s;
        tc8[k] = (_Float16)(bet[fb + k] - mu * s);
    }
    const half8 zero8 = {0, 0, 0, 0, 0, 0, 0, 0};
    const char* zb = (const char*)z;
    unsigned fb2 = (unsigned)fb << 1;
    float acc[8] = {0.f, 0.f, 0.f, 0.f, 0.f, 0.f, 0.f, 0.f};
    int end = off[wid + 1];
    int e = off[wid] + hf;
    for (; e + 14 < end; e += 16) {
        half8 v0 = *(const half8*)(zb + (((unsigned)srcs[e] << 9) + fb2));
        half8 v1 = *(const half8*)(zb + (((unsigned)srcs[e + 2] << 9) + fb2));
        half8 v2 = *(const half8*)(zb + (((unsigned)srcs[e + 4] << 9) + fb2));
        half8 v3 = *(const half8*)(zb + (((unsigned)srcs[e + 6] << 9) + fb2));
        half8 v4 = *(const half8*)(zb + (((unsigned)srcs[e + 8] << 9) + fb2));
        half8 v5 = *(const half8*)(zb + (((unsigned)srcs[e + 10] << 9) + fb2));
        half8 v6 = *(const half8*)(zb + (((unsigned)srcs[e + 12] << 9) + fb2));
        half8 v7 = *(const half8*)(zb + (((unsigned)srcs[e + 14] << 9) + fb2));
        half8 r0 = __builtin_elementwise_max(v0 * sc8 + tc8, zero8);
        half8 r1 = __builtin_elementwise_max(v1 * sc8 + tc8, zero8);
        half8 r2 = __builtin_elementwise_max(v2 * sc8 + tc8, zero8);
        half8 r3 = __builtin_elementwise_max(v3 * sc8 + tc8, zero8);
        half8 r4 = __builtin_elementwise_max(v4 * sc8 + tc8, zero8);
        half8 r5 = __builtin_elementwise_max(v5 * sc8 + tc8, zero8);
        half8 r6 = __builtin_elementwise_max(v6 * sc8 + tc8, zero8);
        half8 r7 = __builtin_elementwise_max(v7 * sc8 + tc8, zero8);
#pragma unroll
        for (int k = 0; k < 8; ++k)
            acc[k] += (((float)r0[k] + (float)r1[k]) + ((float)r2[k] + (float)r3[k]))
                    + (((float)r4[k] + (float)r5[k]) + ((float)r6[k] + (float)r7[k]));
    }
    for (; e + 6 < end; e += 8) {
        half8 v0 = *(const half8*)(zb + (((unsigned)srcs[e] << 9) + fb2));
        half8 v1 = *(const half8*)(zb + (((unsigned)srcs[e + 2] << 9) + fb2));
        half8 v2 = *(const half8*)(zb + (((unsigned)srcs[e + 4] << 9) + fb2));
        half8 v3 = *(const half8*)(zb + (((unsigned)srcs[e + 6] << 9) + fb2));
        half8 r0 = __builtin_elementwise_max(v0 * sc8 + tc8, zero8);
        half8 r1 = __builtin_elementwise_max(v1 * sc8 + tc8, zero8);
        half8 r2 = __builtin_elementwise_max(v2 * sc8 + tc8, zero8);
        half8 r3 = __builtin_elementwise_max(v3 * sc8 + tc8, zero8);
#pragma unroll
        for (int k = 0; k < 8; ++k)
            acc[k] += ((float)r0[k] + (float)r1[k]) + ((float)r2[k] + (float)r3[k]);
    }
    for (; e < end; e += 2) {
        half8 v0 = *(const half8*)(zb + (((unsigned)srcs[e] << 9) + fb2));
        half8 r0 = __builtin_elementwise_max(v0 * sc8 + tc8, zero8);
#pragma unroll
        for (int k = 0; k < 8; ++k) acc[k] += (float)r0[k];
    }
    if (hf == 0) {
        half8 v = *(const half8*)(zb + (((unsigned)wid << 9) + fb2));
        half8 r = __builtin_elementwise_max(v * sc8 + tc8, zero8);
#pragma unroll
        for (int k = 0; k < 8; ++k) acc[k] += (float)r[k];
    }
#pragma unroll
    for (int k = 0; k < 8; ++k) acc[k] += __shfl_xor(acc[k], 32);
    if (hf == 0) {
        half8 o;
#pragma unroll
        for (int k = 0; k < 8; ++k) o[k] = (_Float16)acc[k];
        *(half8*)(out + (size_t)wid * 256 + fb) = o;
    }
}

// ---------------------------------------------------------------- GEMM (fp16 MFMA)
// Round-8: BN=256 full-width blocks (A read ONCE), K-chunked weight staging:
// chunks of [256 cols][64 k] = 32KB swizzled LDS, K/64 chunks. Epilogue: stats
// (separate 16KB LDS region) + two 128-col LDS-staged coalesced store phases.
template <int K, int WITH_STATS>
__global__ __launch_bounds__(512, 4) void gemm_kernel(
    const _Float16* __restrict__ A, const _Float16* __restrict__ BT,
    const float* __restrict__ bias, _Float16* __restrict__ Y,
    float* __restrict__ stats, int M) {
    extern __shared__ _Float16 blds[];       // region0: weights chunk / ostage
    float* sred = (float*)(blds + 17408);    // region1 @34816B: [2][8][256] f32
    const int tid = threadIdx.x;
    const int lane = tid & 63, wave = tid >> 6;
    const int i = lane & 15, g = lane >> 4;
    const int rowbase = blockIdx.x * 128 + wave * 16;
    const int arow = min(rowbase + i, M - 1);

    half8 afrag[K / 32];
#pragma unroll
    for (int s = 0; s < K / 32; ++s)
        afrag[s] = *(const half8*)(A + (size_t)arow * K + s * 32 + g * 8);

    f32x4 acc[16];
#pragma unroll
    for (int t = 0; t < 16; ++t) acc[t] = (f32x4){0.f, 0.f, 0.f, 0.f};

    const int scol = tid >> 1;               // staging: 2 threads per col
    const int shalf = (tid & 1) * 32;
    const int ssw = (scol & 7) << 3;
    const int swi = (i & 7) << 3;

#pragma unroll
    for (int kc = 0; kc < K / 64; ++kc) {
        if (kc) __syncthreads();             // prior chunk's reads done
        {   // stage [256][64] chunk, XOR-swizzled within 64-half rows
            const _Float16* src = BT + (size_t)scol * K + kc * 64 + shalf;
            _Float16* dst = blds + scol * 64;
#pragma unroll
            for (int c = 0; c < 32; c += 8)
                *(half8*)(dst + ((shalf + c) ^ ssw)) = *(const half8*)(src + c);
        }
        __syncthreads();
#pragma unroll
        for (int ks = 0; ks < 2; ++ks)
#pragma unroll
            for (int t = 0; t < 16; ++t) {
                half8 b = *(const half8*)(blds + (t * 16 + i) * 64 + ((ks * 32 + g * 8) ^ swi));
                acc[t] = __builtin_amdgcn_mfma_f32_16x16x32_f16(afrag[kc * 2 + ks], b, acc[t], 0, 0, 0);
            }
    }

    const int rg = g * 4;
    if (WITH_STATS) {                        // region1 disjoint from weights: no barrier needed
#pragma unroll
        for (int t = 0; t < 16; ++t) {
            int c = t * 16 + i;
            float bv = bias[c];
            float s1 = 0.f, s2 = 0.f;
#pragma unroll
            for (int j = 0; j < 4; ++j) {
                if (rowbase + rg + j < M) {
                    float v = acc[t][j] + bv;
                    s1 += v;
                    s2 += v * v;
                }
            }
            s1 += __shfl_xor(s1, 16); s1 += __shfl_xor(s1, 32);
            s2 += __shfl_xor(s2, 16); s2 += __shfl_xor(s2, 32);
            if (g == 0) {
                sred[wave * 256 + c] = s1;
                sred[2048 + wave * 256 + c] = s2;
            }
        }
    }
    __syncthreads();                         // weights dead + sred visible
    if (WITH_STATS) {                        // one atomic per column per block
        int which = tid >> 8, c = tid & 255;
        float s = 0.f;
#pragma unroll
        for (int w = 0; w < 8; ++w) s += sred[which * 2048 + w * 256 + c];
        atomicAdd(&stats[which * 256 + c], s);
    }

    // two coalesced store phases, 128 cols each, via ostage [128][136]
    _Float16* ostage = blds;
#pragma unroll
    for (int ph = 0; ph < 2; ++ph) {
        if (ph) __syncthreads();             // phase-0 copy-out done
#pragma unroll
        for (int tt = 0; tt < 8; ++tt) {
            int t = ph * 8 + tt;
            int lc = tt * 16 + i;
            float bv = bias[t * 16 + i];
#pragma unroll
            for (int j = 0; j < 4; ++j) {
                float v = acc[t][j] + bv;
                if (WITH_STATS == 0) v = fmaxf(v, 0.f);
                ostage[(wave * 16 + rg + j) * 136 + lc] = (_Float16)v;
            }
        }
        __syncthreads();
#pragma unroll
        for (int k = 0; k < 4; ++k) {
            int ch = k * 512 + tid;
            int rl = ch >> 4, pc = (ch & 15) << 3;
            int r = blockIdx.x * 128 + rl;
            if (r < M)
                *(half8*)(Y + (size_t)r * 256 + ph * 128 + pc) =
                    *(const half8*)(ostage + rl * 136 + pc);
        }
    }
}

// ---------------------------------------------------------------- pooling
__global__ void graph_bounds(const int* __restrict__ batch, int* __restrict__ gstart, int N) {
    int t = threadIdx.x;
    if (t > NGRAPH) return;
    if (t == NGRAPH) { gstart[t] = N; return; }
    int lo = 0, hi = N;
    while (lo < hi) { int m = (lo + hi) >> 1; if (batch[m] < t) lo = m + 1; else hi = m; }
    gstart[t] = lo;
}

#define PCHUNK 256
__global__ void pool_stage1(const _Float16* __restrict__ z, const int* __restrict__ batch,
                            const int* __restrict__ gstart, const float* __restrict__ stats,
                            const float* __restrict__ gam, const float* __restrict__ bet,
                            float* __restrict__ acc, int N, float invN) {
    __shared__ float lds[8 * 512];
    int c0 = blockIdx.x * PCHUNK;
    int cend = min(c0 + PCHUNK, N);
    int tid = threadIdx.x;
    int rowlane = tid >> 5;
    int fb = (tid & 31) << 3;
    float sc[8], tc[8];
#pragma unroll
    for (int k = 0; k < 8; ++k) {
        float mu = stats[fb + k] * invN;
        float var = stats[256 + fb + k] * invN - mu * mu;
        float s = gam[fb + k] * rsqrtf(var + BN_EPS);
        sc[k] = s;
        tc[k] = bet[fb + k] - mu * s;
    }
    int segs = c0;
    while (segs < cend) {
        int g = batch[segs];
        int sege = min(gstart[g + 1], cend);
        float a[8] = {0.f, 0.f, 0.f, 0.f, 0.f, 0.f, 0.f, 0.f};
        for (int r = segs + rowlane; r < sege; r += 16) {
            half8 v = *(const half8*)(z + (size_t)r * 256 + fb);
#pragma unroll
            for (int k = 0; k < 8; ++k)
                a[k] += fmaxf(fmaf((float)v[k], sc[k], tc[k]), 0.f);
        }
#pragma unroll
        for (int k = 0; k < 8; ++k) lds[k * 512 + tid] = a[k];
        __syncthreads();
#pragma unroll
        for (int d = 8; d > 0; d >>= 1) {
            if (rowlane < d) {
#pragma unroll
                for (int k = 0; k < 8; ++k)
                    lds[k * 512 + tid] += lds[k * 512 + tid + d * 32];
            }
            __syncthreads();
        }
        if (rowlane == 0) {
#pragma unroll
            for (int k = 0; k < 8; ++k)
                atomicAdd(&acc[g * 256 + fb + k], lds[k * 512 + tid]);
        }
        __syncthreads();
        segs = sege;
    }
}

__global__ void pool_finalize(const float* __restrict__ acc, const int* __restrict__ gstart,
                              float* __restrict__ out) {
    int i = blockIdx.x * 256 + threadIdx.x;
    int g = i >> 8;
    int c = gstart[g + 1] - gstart[g];
    out[i] = acc[i] / (float)(c > 0 ? c : 1);
}

// ---------------------------------------------------------------- launch
extern "C" void kernel_launch(void* const* d_in, const int* in_sizes, int n_in,
                              void* d_out, int out_size, void* d_ws, size_t ws_size,
                              hipStream_t stream) {
    const float* x    = (const float*)d_in[0];
    const int*   ei   = (const int*)d_in[1];
    const int*   batch= (const int*)d_in[2];
    const float* w1_0 = (const float*)d_in[3];
    const float* b1_0 = (const float*)d_in[4];
    const float* w2_0 = (const float*)d_in[5];
    const float* b2_0 = (const float*)d_in[6];
    const float* g_0  = (const float*)d_in[7];
    const float* be_0 = (const float*)d_in[8];
    const float* w1_r = (const float*)d_in[9];
    const float* b1_r = (const float*)d_in[10];
    const float* w2_r = (const float*)d_in[11];
    const float* b2_r = (const float*)d_in[12];
    const float* g_r  = (const float*)d_in[13];
    const float* be_r = (const float*)d_in[14];

    const int N = in_sizes[0] / 128;   // 50000
    const int E = in_sizes[1] / 2;     // 800000

    char* p = (char*)d_ws;
    auto alloc = [&](size_t bytes) { char* r = p; p += (bytes + 255) & ~(size_t)255; return r; };
    float*    stats   = (float*)alloc(4 * 512 * sizeof(float));
    int*      part    = (int*)alloc(256 * sizeof(int));
    int*      off     = (int*)alloc((size_t)(N + 1) * sizeof(int));
    int*      cnt     = (int*)alloc((size_t)N * sizeof(int));
    int*      gstart  = (int*)alloc(65 * sizeof(int));
    float*    accp    = (float*)alloc(NGRAPH * 256 * sizeof(float));
    int*      rank    = (int*)alloc((size_t)E * sizeof(int));
    int*      csr_src = (int*)alloc((size_t)E * sizeof(int));
    _Float16* wT      = (_Float16*)alloc((size_t)491520 * sizeof(_Float16));
    _Float16* x16     = (_Float16*)alloc((size_t)N * 128 * sizeof(_Float16));
    _Float16* zin     = (_Float16*)alloc((size_t)N * 256 * sizeof(_Float16));
    _Float16* y       = (_Float16*)alloc((size_t)N * 256 * sizeof(_Float16));
    _Float16* z       = (_Float16*)alloc((size_t)N * 256 * sizeof(_Float16));

    hipMemsetAsync(stats, 0, 4 * 512 * sizeof(float), stream);
    hipMemsetAsync(cnt, 0, (size_t)N * sizeof(int), stream);
    hipMemsetAsync(accp, 0, NGRAPH * 256 * sizeof(float), stream);

    PrepArgs pa;
    pa.src[0] = w1_0;  pa.dst[0] = wT;           pa.K[0] = 128;
    pa.src[1] = w2_0;  pa.dst[1] = wT + 32768;   pa.K[1] = 256;
    for (int i = 0; i < 3; ++i) {
        pa.src[2 + i] = w1_r + (size_t)i * 65536; pa.dst[2 + i] = wT + 98304 + (size_t)i * 65536; pa.K[2 + i] = 256;
        pa.src[5 + i] = w2_r + (size_t)i * 65536; pa.dst[5 + i] = wT + 294912 + (size_t)i * 65536; pa.K[5 + i] = 256;
    }
    prep_weights<<<dim3(256, 8), 256, 0, stream>>>(pa);
    cast_x<<<(N * 128 / 8 + 255) / 256, 256, 0, stream>>>(x, x16, N * 128);

    const int eb = (E + 255) / 256;
    const int nb = (N + 255) / 256;
    edge_count<<<eb, 256, 0, stream>>>(ei, cnt, rank, E);
    scan_p1<<<nb, 256, 0, stream>>>(cnt, part, N);
    scan_p2<<<1, 256, 0, stream>>>(part, off, N, nb);
    scan_p3<<<nb, 256, 0, stream>>>(cnt, part, off, N);
    edge_fill<<<eb, 256, 0, stream>>>(ei, off, rank, csr_src, E);
    graph_bounds<<<1, 128, 0, stream>>>(batch, gstart, N);

    const int gwb = (N + 3) / 4;
    const int gemmg = (N + 127) / 128;         // 391 blocks, BN=256
    const int ldsb = 51200;                    // 34816 ostage/weights + 16384 sred
    const float invN = 1.0f / (float)N;

    // ---- layer 0
    gather0<<<gwb, 256, 0, stream>>>(x16, off, csr_src, zin, N);
    gemm_kernel<128, 0><<<gemmg, 512, ldsb, stream>>>(zin, wT, b1_0, y, nullptr, N);
    gemm_kernel<256, 1><<<gemmg, 512, ldsb, stream>>>(y, wT + 32768, b2_0, z, stats, N);

    // ---- layers 1..3 (BN of previous layer fused into gather)
    const float* cur_stats = stats;
    const float* cur_g = g_0;
    const float* cur_be = be_0;
    for (int i = 0; i < 3; ++i) {
        gather_fused<<<gwb, 256, 0, stream>>>(z, off, csr_src, cur_stats, cur_g, cur_be, zin, N, invN);
        gemm_kernel<256, 0><<<gemmg, 512, ldsb, stream>>>(
            zin, wT + 98304 + (size_t)i * 65536, b1_r + i * 256, y, nullptr, N);
        gemm_kernel<256, 1><<<gemmg, 512, ldsb, stream>>>(
            y, wT + 294912 + (size_t)i * 65536, b2_r + i * 256, z, stats + (i + 1) * 512, N);
        cur_stats = stats + (i + 1) * 512;
        cur_g = g_r + i * 256;
        cur_be = be_r + i * 256;
    }

    // ---- pool (BN of last layer fused)
    pool_stage1<<<(N + PCHUNK - 1) / PCHUNK, 512, 0, stream>>>(
        z, batch, gstart, cur_stats, cur_g, cur_be, accp, N, invN);
    pool_finalize<<<NGRAPH, 256, 0, stream>>>(accp, gstart, (float*)d_out);
}